// Round 1
// baseline (355.971 us; speedup 1.0000x reference)
//
#include <hip/hip_runtime.h>
#include <hip/hip_bf16.h>
#include <stdint.h>

typedef __attribute__((ext_vector_type(4))) float f32x4;
typedef __attribute__((ext_vector_type(8))) short s16x8;

#define DEVI __device__ __forceinline__

DEVI short f2b(float f) {
    union { float f; unsigned u; } v; v.f = f;
    unsigned r = v.u + 0x7fffu + ((v.u >> 16) & 1u);
    return (short)(r >> 16);
}

// ---------------- weight convert: 5 x [1024x1024] f32 -> bf16 ----------------
struct Ptr5 { const float* p[5]; };

__global__ __launch_bounds__(256) void cvtW(Ptr5 src, short* __restrict__ dst) {
    const float* s = src.p[blockIdx.y];
    short* d = dst + (size_t)blockIdx.y * (1024u * 1024u);
    int i = (blockIdx.x * 256 + threadIdx.x) * 8;
    f32x4 a = *(const f32x4*)(s + i);
    f32x4 b = *(const f32x4*)(s + i + 4);
    s16x8 o;
#pragma unroll
    for (int j = 0; j < 4; ++j) { o[j] = f2b(a[j]); o[4 + j] = f2b(b[j]); }
    *(s16x8*)(d + i) = o;
}

// ---------------- NT GEMM: C[M=8192][N=1024] = A[M][K] * W[N][K]^T + bias ----
// AF32: A is f32 (convert to bf16 during staging), else bf16.
// OUTF32: write f32, else bf16. TWO: C = A0*W0^T + A1*W1^T + b0 + b1 (K=2*1024).
template<int AF32, int OUTF32, int TWO>
__global__ __launch_bounds__(256) void gemm_nt(
    const void* __restrict__ A0_, const void* __restrict__ A1_,
    const short* __restrict__ W0, const short* __restrict__ W1,
    const float* __restrict__ b0, const float* __restrict__ b1,
    void* __restrict__ C_)
{
    constexpr int K = 1024, N = 1024;
    const int tid = threadIdx.x;
    const int lane = tid & 63, wid = tid >> 6;
    const int wm = wid >> 1, wn = wid & 1;
    const int r = lane & 15, g = lane >> 4;
    const int m0 = blockIdx.y * 128, n0 = blockIdx.x * 128;

    __shared__ alignas(16) short As[2][128 * 32];
    __shared__ alignas(16) short Ws[2][128 * 32];

    const int srow = tid >> 1, shalf = tid & 1;   // staging: 128 rows x 32 cols, 16 elems/thread

    // fragment LDS byte offsets (swizzle: slot ^= (row>>1)&3, 16B slots in 64B rows)
    int aoff[4], boff[4];
#pragma unroll
    for (int f = 0; f < 4; ++f) {
        int ra = wm * 64 + f * 16 + r;
        aoff[f] = ra * 64 + ((g ^ ((ra >> 1) & 3)) << 4);
        int rb = wn * 64 + f * 16 + r;
        boff[f] = rb * 64 + ((g ^ ((rb >> 1) & 3)) << 4);
    }

    f32x4 z = {0.f, 0.f, 0.f, 0.f};
    f32x4 acc[4][4];
#pragma unroll
    for (int i = 0; i < 4; ++i)
#pragma unroll
        for (int j = 0; j < 4; ++j) acc[i][j] = z;

    // staging regs
    f32x4 a0g, a1g, a2g, a3g;
    s16x8 ab0, ab1, wg0, wg1;

    auto load_regs = [&](int kt) {
        int kk = kt * 32;
        const short* Wp = W0; const void* Ap = A0_;
        if (TWO && kk >= 1024) { Wp = W1; Ap = A1_; }
        int ko = kk & 1023;
        const short* wp = Wp + (size_t)(n0 + srow) * K + ko + shalf * 16;
        wg0 = *(const s16x8*)wp;
        wg1 = *(const s16x8*)(wp + 8);
        if constexpr (AF32) {
            const float* ap = (const float*)Ap + (size_t)(m0 + srow) * K + ko + shalf * 16;
            a0g = *(const f32x4*)ap;       a1g = *(const f32x4*)(ap + 4);
            a2g = *(const f32x4*)(ap + 8); a3g = *(const f32x4*)(ap + 12);
        } else {
            const short* ap = (const short*)Ap + (size_t)(m0 + srow) * K + ko + shalf * 16;
            ab0 = *(const s16x8*)ap;
            ab1 = *(const s16x8*)(ap + 8);
        }
    };

    auto store_lds = [&](int buf) {
        int sw = (srow >> 1) & 3;
        int ph0 = (shalf * 2) ^ sw, ph1 = (shalf * 2 + 1) ^ sw;
        s16x8 s0, s1;
        if constexpr (AF32) {
#pragma unroll
            for (int j = 0; j < 4; ++j) {
                s0[j] = f2b(a0g[j]); s0[4 + j] = f2b(a1g[j]);
                s1[j] = f2b(a2g[j]); s1[4 + j] = f2b(a3g[j]);
            }
        } else { s0 = ab0; s1 = ab1; }
        char* ab = (char*)As[buf];
        *(s16x8*)(ab + srow * 64 + ph0 * 16) = s0;
        *(s16x8*)(ab + srow * 64 + ph1 * 16) = s1;
        char* wb = (char*)Ws[buf];
        *(s16x8*)(wb + srow * 64 + ph0 * 16) = wg0;
        *(s16x8*)(wb + srow * 64 + ph1 * 16) = wg1;
    };

    auto compute = [&](int buf) {
        s16x8 af[4], bfr[4];
#pragma unroll
        for (int f = 0; f < 4; ++f) {
            af[f]  = *(const s16x8*)((char*)As[buf] + aoff[f]);
            bfr[f] = *(const s16x8*)((char*)Ws[buf] + boff[f]);
        }
#pragma unroll
        for (int i = 0; i < 4; ++i)
#pragma unroll
            for (int j = 0; j < 4; ++j)
                acc[i][j] = __builtin_amdgcn_mfma_f32_16x16x32_bf16(af[i], bfr[j], acc[i][j], 0, 0, 0);
    };

    constexpr int NK = TWO ? 64 : 32;
    load_regs(0);
    store_lds(0);
    __syncthreads();
    int buf = 0;
    for (int kt = 0; kt < NK; ++kt) {
        if (kt + 1 < NK) load_regs(kt + 1);   // issue global loads, overlap with compute
        compute(buf);
        if (kt + 1 < NK) store_lds(buf ^ 1);
        __syncthreads();
        buf ^= 1;
    }

    // epilogue: C layout col=lane&15, row=(lane>>4)*4+reg
#pragma unroll
    for (int j = 0; j < 4; ++j) {
        int col = n0 + wn * 64 + j * 16 + r;
        float bb = b0[col];
        if (TWO) bb += b1[col];
#pragma unroll
        for (int i = 0; i < 4; ++i) {
            int rowb = m0 + wm * 64 + i * 16 + g * 4;
#pragma unroll
            for (int q = 0; q < 4; ++q) {
                float val = acc[i][j][q] + bb;
                if constexpr (OUTF32)
                    ((float*)C_)[(size_t)(rowb + q) * N + col] = val;
                else
                    ((short*)C_)[(size_t)(rowb + q) * N + col] = f2b(val);
            }
        }
    }
}

// ---------------- flash attention ----------------
// grid: (B*NH=128, S/64=16); block 256 = 4 waves, wave handles 16 q-rows.
__global__ __launch_bounds__(256) void attn_fwd(
    const short* __restrict__ qrh, const short* __restrict__ kh,
    const short* __restrict__ vh, const int* __restrict__ mask,
    short* __restrict__ outp)
{
    const int bh = blockIdx.x;
    const int b = bh >> 4, h = bh & 15;
    const int qt = blockIdx.y;
    const int tid = threadIdx.x, lane = tid & 63, wid = tid >> 6;
    const int r = lane & 15, g = lane >> 4;

    __shared__ alignas(16) short Ks[64 * 64];      // swizzled [tok][dk]
    __shared__ alignas(16) short Vt[64 * 72];      // transposed [dk][tok], pad 72
    __shared__ alignas(16) short Ps[4][16 * 72];   // per-wave P, pad 72
    __shared__ float mb[64];

    const int q0 = qt * 64 + wid * 16;
    const short* qbase = qrh + (size_t)(b * 1024 + q0 + r) * 1024 + h * 64;
    s16x8 qf0 = *(const s16x8*)(qbase + g * 8);
    s16x8 qf1 = *(const s16x8*)(qbase + 32 + g * 8);

    f32x4 z = {0.f, 0.f, 0.f, 0.f};
    f32x4 oacc[4];
    float mrun[4], lrun[4];
#pragma unroll
    for (int i = 0; i < 4; ++i) { oacc[i] = z; mrun[i] = -1e30f; lrun[i] = 0.f; }

    const int krow = tid >> 2, kq = tid & 3;   // K staging: 64 rows x 4 quarters
    const int vtok = tid & 63, vd = tid >> 6;  // V staging: 64 toks x 4 d-quarters

    for (int t = 0; t < 16; ++t) {
        const int k0 = t * 64;
        if (t) __syncthreads();
        {   // stage K tile, swizzle slot ^= row&7 (128B rows, 8x16B slots)
            const short* kp = kh + (size_t)(b * 1024 + k0 + krow) * 1024 + h * 64 + kq * 16;
            s16x8 k0v = *(const s16x8*)kp;
            s16x8 k1v = *(const s16x8*)(kp + 8);
            char* kb = (char*)Ks;
            int p0 = (kq * 2) ^ (krow & 7), p1 = (kq * 2 + 1) ^ (krow & 7);
            *(s16x8*)(kb + krow * 128 + p0 * 16) = k0v;
            *(s16x8*)(kb + krow * 128 + p1 * 16) = k1v;
        }
        {   // stage V transposed
            const short* vp = vh + (size_t)(b * 1024 + k0 + vtok) * 1024 + h * 64 + vd * 16;
            s16x8 v0 = *(const s16x8*)vp;
            s16x8 v1 = *(const s16x8*)(vp + 8);
#pragma unroll
            for (int i = 0; i < 8; ++i) {
                Vt[(vd * 16 + i) * 72 + vtok] = v0[i];
                Vt[(vd * 16 + 8 + i) * 72 + vtok] = v1[i];
            }
        }
        if (tid < 64) mb[tid] = mask[b * 1024 + k0 + tid] ? -1e9f : 0.f;
        __syncthreads();

        // QK^T: scores[16q][64tok]
        f32x4 sf[4];
#pragma unroll
        for (int fn = 0; fn < 4; ++fn) {
            int row = fn * 16 + r;
            char* kb = (char*)Ks;
            s16x8 kfa = *(const s16x8*)(kb + row * 128 + ((g ^ (row & 7)) << 4));
            s16x8 kfb = *(const s16x8*)(kb + row * 128 + (((4 + g) ^ (row & 7)) << 4));
            f32x4 c = __builtin_amdgcn_mfma_f32_16x16x32_bf16(qf0, kfa, z, 0, 0, 0);
            sf[fn] = __builtin_amdgcn_mfma_f32_16x16x32_bf16(qf1, kfb, c, 0, 0, 0);
        }

        // scale + mask + row max
        float tmax[4] = {-3e38f, -3e38f, -3e38f, -3e38f};
#pragma unroll
        for (int fn = 0; fn < 4; ++fn) {
            float mv = mb[fn * 16 + r];
#pragma unroll
            for (int q = 0; q < 4; ++q) {
                float s = sf[fn][q] * 0.125f + mv;
                sf[fn][q] = s;
                tmax[q] = fmaxf(tmax[q], s);
            }
        }
#pragma unroll
        for (int d = 1; d < 16; d <<= 1)
#pragma unroll
            for (int q = 0; q < 4; ++q)
                tmax[q] = fmaxf(tmax[q], __shfl_xor(tmax[q], d));

        float corr[4], tsum[4];
#pragma unroll
        for (int q = 0; q < 4; ++q) {
            float mn = fmaxf(mrun[q], tmax[q]);
            corr[q] = __expf(mrun[q] - mn);
            mrun[q] = mn;
            tsum[q] = 0.f;
        }
        // P = exp(s - m), write to per-wave LDS (C-layout -> A-layout transpose)
#pragma unroll
        for (int fn = 0; fn < 4; ++fn) {
#pragma unroll
            for (int q = 0; q < 4; ++q) {
                float p = __expf(sf[fn][q] - mrun[q]);
                tsum[q] += p;
                Ps[wid][(g * 4 + q) * 72 + fn * 16 + r] = f2b(p);
            }
        }
#pragma unroll
        for (int d = 1; d < 16; d <<= 1)
#pragma unroll
            for (int q = 0; q < 4; ++q)
                tsum[q] += __shfl_xor(tsum[q], d);
#pragma unroll
        for (int q = 0; q < 4; ++q) {
            lrun[q] = lrun[q] * corr[q] + tsum[q];
#pragma unroll
            for (int df = 0; df < 4; ++df) oacc[df][q] *= corr[q];
        }

        // PV: O[16q][64d] += P[16q][64tok] * V[64tok][64d]
#pragma unroll
        for (int ks = 0; ks < 2; ++ks) {
            s16x8 pa = *(const s16x8*)((char*)Ps[wid] + (r * 72 + ks * 32 + g * 8) * 2);
#pragma unroll
            for (int df = 0; df < 4; ++df) {
                s16x8 vb = *(const s16x8*)((char*)Vt + ((df * 16 + r) * 72 + ks * 32 + g * 8) * 2);
                oacc[df] = __builtin_amdgcn_mfma_f32_16x16x32_bf16(pa, vb, oacc[df], 0, 0, 0);
            }
        }
    }

    // epilogue
#pragma unroll
    for (int df = 0; df < 4; ++df)
#pragma unroll
        for (int q = 0; q < 4; ++q) {
            float v = oacc[df][q] / lrun[q];
            outp[(size_t)(b * 1024 + q0 + g * 4 + q) * 1024 + h * 64 + df * 16 + r] = f2b(v);
        }
}

// ---------------- launch ----------------
extern "C" void kernel_launch(void* const* d_in, const int* in_sizes, int n_in,
                              void* d_out, int out_size, void* d_ws, size_t ws_size,
                              hipStream_t stream) {
    const float* v  = (const float*)d_in[0];
    const float* k  = (const float*)d_in[1];
    const float* q  = (const float*)d_in[2];
    const float* rr = (const float*)d_in[3];
    const int* mask = (const int*)d_in[4];
    const float* Wv = (const float*)d_in[5];  const float* bv = (const float*)d_in[6];
    const float* Wk = (const float*)d_in[7];  const float* bk = (const float*)d_in[8];
    const float* Wq = (const float*)d_in[9];  const float* bq = (const float*)d_in[10];
    const float* Wr = (const float*)d_in[11]; const float* br = (const float*)d_in[12];
    const float* Wm = (const float*)d_in[13]; const float* bm = (const float*)d_in[14];

    const size_t NEED = 10485760u + 4u * 16777216u;   // 5 bf16 weights + 4 bf16 activations
    if (ws_size < NEED) return;                       // leaves poison -> visible failure

    char* ws = (char*)d_ws;
    short* Wb  = (short*)ws;                          // 5 x 1M bf16
    short* vhb = (short*)(ws + 10485760u);
    short* khb = vhb + 8388608u;
    short* qrb = khb + 8388608u;
    short* att = qrb + 8388608u;

    Ptr5 p5;
    p5.p[0] = Wv; p5.p[1] = Wk; p5.p[2] = Wq; p5.p[3] = Wr; p5.p[4] = Wm;
    cvtW<<<dim3(512, 5), 256, 0, stream>>>(p5, Wb);

    dim3 gg(8, 64);   // N/128, M/128
    gemm_nt<1, 0, 0><<<gg, 256, 0, stream>>>(v,  nullptr, Wb,                nullptr,           bv, nullptr, vhb);
    gemm_nt<1, 0, 0><<<gg, 256, 0, stream>>>(k,  nullptr, Wb + 1048576u,     nullptr,           bk, nullptr, khb);
    gemm_nt<1, 0, 1><<<gg, 256, 0, stream>>>(q,  rr,      Wb + 2u * 1048576u, Wb + 3u * 1048576u, bq, br,     qrb);

    attn_fwd<<<dim3(128, 16), 256, 0, stream>>>(qrb, khb, vhb, mask, att);

    gemm_nt<0, 1, 0><<<gg, 256, 0, stream>>>(att, nullptr, Wb + 4u * 1048576u, nullptr, bm, nullptr, (float*)d_out);
}

// Round 2
// 301.348 us; speedup vs baseline: 1.1813x; 1.1813x over previous
//
#include <hip/hip_runtime.h>
#include <hip/hip_bf16.h>
#include <stdint.h>

typedef __attribute__((ext_vector_type(4))) float f32x4;
typedef __attribute__((ext_vector_type(8))) short s16x8;
typedef __attribute__((ext_vector_type(4))) short s16x4;

#define DEVI __device__ __forceinline__

DEVI short f2b(float f) {
    union { float f; unsigned u; } v; v.f = f;
    unsigned r = v.u + 0x7fffu + ((v.u >> 16) & 1u);
    return (short)(r >> 16);
}

// ---------------- weight convert: 5 x [1024x1024] f32 -> bf16 ----------------
struct Ptr5 { const float* p[5]; };

__global__ __launch_bounds__(256) void cvtW(Ptr5 src, short* __restrict__ dst) {
    const float* s = src.p[blockIdx.y];
    short* d = dst + (size_t)blockIdx.y * (1024u * 1024u);
    int i = (blockIdx.x * 256 + threadIdx.x) * 8;
    f32x4 a = *(const f32x4*)(s + i);
    f32x4 b = *(const f32x4*)(s + i + 4);
    s16x8 o;
#pragma unroll
    for (int j = 0; j < 4; ++j) { o[j] = f2b(a[j]); o[4 + j] = f2b(b[j]); }
    *(s16x8*)(d + i) = o;
}

// ---------------- NT GEMM: C[M=8192][N=1024] = A[M][K] * W[N][K]^T + bias ----
// AF32: A is f32 (convert to bf16 during staging), else bf16.
// OUTMODE: 0 = bf16 row-major, 1 = f32 row-major, 2 = bf16 per-head-transposed
//          [b][h][d][tok] (for attention V).
// TWO: C = A0*W0^T + A1*W1^T + b0 + b1 (K=2*1024).
template<int AF32, int OUTMODE, int TWO>
__global__ __launch_bounds__(256) void gemm_nt(
    const void* __restrict__ A0_, const void* __restrict__ A1_,
    const short* __restrict__ W0, const short* __restrict__ W1,
    const float* __restrict__ b0, const float* __restrict__ b1,
    void* __restrict__ C_)
{
    constexpr int K = 1024, N = 1024;
    const int tid = threadIdx.x;
    const int lane = tid & 63, wid = tid >> 6;
    const int wm = wid >> 1, wn = wid & 1;
    const int r = lane & 15, g = lane >> 4;
    const int m0 = blockIdx.y * 128, n0 = blockIdx.x * 128;

    __shared__ alignas(16) short As[2][128 * 32];
    __shared__ alignas(16) short Ws[2][128 * 32];

    const int srow = tid >> 1, shalf = tid & 1;   // staging: 128 rows x 32 cols, 16 elems/thread

    // fragment LDS byte offsets (swizzle: slot ^= (row>>1)&3, 16B slots in 64B rows)
    int aoff[4], boff[4];
#pragma unroll
    for (int f = 0; f < 4; ++f) {
        int ra = wm * 64 + f * 16 + r;
        aoff[f] = ra * 64 + ((g ^ ((ra >> 1) & 3)) << 4);
        int rb = wn * 64 + f * 16 + r;
        boff[f] = rb * 64 + ((g ^ ((rb >> 1) & 3)) << 4);
    }

    f32x4 z = {0.f, 0.f, 0.f, 0.f};
    f32x4 acc[4][4];
#pragma unroll
    for (int i = 0; i < 4; ++i)
#pragma unroll
        for (int j = 0; j < 4; ++j) acc[i][j] = z;

    // staging regs
    f32x4 a0g, a1g, a2g, a3g;
    s16x8 ab0, ab1, wg0, wg1;

    auto load_regs = [&](int kt) {
        int kk = kt * 32;
        const short* Wp = W0; const void* Ap = A0_;
        if (TWO && kk >= 1024) { Wp = W1; Ap = A1_; }
        int ko = kk & 1023;
        const short* wp = Wp + (size_t)(n0 + srow) * K + ko + shalf * 16;
        wg0 = *(const s16x8*)wp;
        wg1 = *(const s16x8*)(wp + 8);
        if constexpr (AF32) {
            const float* ap = (const float*)Ap + (size_t)(m0 + srow) * K + ko + shalf * 16;
            a0g = *(const f32x4*)ap;       a1g = *(const f32x4*)(ap + 4);
            a2g = *(const f32x4*)(ap + 8); a3g = *(const f32x4*)(ap + 12);
        } else {
            const short* ap = (const short*)Ap + (size_t)(m0 + srow) * K + ko + shalf * 16;
            ab0 = *(const s16x8*)ap;
            ab1 = *(const s16x8*)(ap + 8);
        }
    };

    auto store_lds = [&](int buf) {
        int sw = (srow >> 1) & 3;
        int ph0 = (shalf * 2) ^ sw, ph1 = (shalf * 2 + 1) ^ sw;
        s16x8 s0, s1;
        if constexpr (AF32) {
#pragma unroll
            for (int j = 0; j < 4; ++j) {
                s0[j] = f2b(a0g[j]); s0[4 + j] = f2b(a1g[j]);
                s1[j] = f2b(a2g[j]); s1[4 + j] = f2b(a3g[j]);
            }
        } else { s0 = ab0; s1 = ab1; }
        char* ab = (char*)As[buf];
        *(s16x8*)(ab + srow * 64 + ph0 * 16) = s0;
        *(s16x8*)(ab + srow * 64 + ph1 * 16) = s1;
        char* wb = (char*)Ws[buf];
        *(s16x8*)(wb + srow * 64 + ph0 * 16) = wg0;
        *(s16x8*)(wb + srow * 64 + ph1 * 16) = wg1;
    };

    auto compute = [&](int buf) {
        s16x8 af[4], bfr[4];
#pragma unroll
        for (int f = 0; f < 4; ++f) {
            af[f]  = *(const s16x8*)((char*)As[buf] + aoff[f]);
            bfr[f] = *(const s16x8*)((char*)Ws[buf] + boff[f]);
        }
#pragma unroll
        for (int i = 0; i < 4; ++i)
#pragma unroll
            for (int j = 0; j < 4; ++j)
                acc[i][j] = __builtin_amdgcn_mfma_f32_16x16x32_bf16(af[i], bfr[j], acc[i][j], 0, 0, 0);
    };

    constexpr int NK = TWO ? 64 : 32;
    load_regs(0);
    store_lds(0);
    __syncthreads();
    int buf = 0;
    for (int kt = 0; kt < NK; ++kt) {
        if (kt + 1 < NK) load_regs(kt + 1);   // issue global loads, overlap with compute
        compute(buf);
        if (kt + 1 < NK) store_lds(buf ^ 1);
        __syncthreads();
        buf ^= 1;
    }

    // epilogue: C layout col=lane&15, row=(lane>>4)*4+reg
#pragma unroll
    for (int j = 0; j < 4; ++j) {
        int col = n0 + wn * 64 + j * 16 + r;
        float bb = b0[col];
        if (TWO) bb += b1[col];
#pragma unroll
        for (int i = 0; i < 4; ++i) {
            int rowb = m0 + wm * 64 + i * 16 + g * 4;
            if constexpr (OUTMODE == 2) {
                // V^T per head: [b][h][d][tok]; 4 consecutive toks -> one b64 store
                int bb_ = rowb >> 10, tok = rowb & 1023;
                short* dst = (short*)C_ + ((size_t)(bb_ * 16 + (col >> 6))) * 65536
                           + (size_t)(col & 63) * 1024 + tok;
                s16x4 o;
#pragma unroll
                for (int q = 0; q < 4; ++q) o[q] = f2b(acc[i][j][q] + bb);
                *(s16x4*)dst = o;
            } else {
#pragma unroll
                for (int q = 0; q < 4; ++q) {
                    float val = acc[i][j][q] + bb;
                    if constexpr (OUTMODE == 1)
                        ((float*)C_)[(size_t)(rowb + q) * N + col] = val;
                    else
                        ((short*)C_)[(size_t)(rowb + q) * N + col] = f2b(val);
                }
            }
        }
    }
}

// ---------------- flash attention (swapped QK^T, in-register softmax) --------
// grid: (B*NH=128, S/64=16); block 256 = 4 waves, wave handles 16 q-rows.
// S^T = mfma(K, Q): lane owns q = lane&15; 16 token-scores per lane in regs.
// PV: out^T = V^T * P^T; P^T B-frag is lane-resident (k-mapping freedom),
// V^T A-frag read as 2x ds_read_b64 from swizzled row-major V^T LDS.
__global__ __launch_bounds__(256) void attn_fwd(
    const short* __restrict__ qrh, const short* __restrict__ kh,
    const short* __restrict__ vT, const int* __restrict__ mask,
    short* __restrict__ outp)
{
    const int bh = blockIdx.x;
    const int b = bh >> 4, h = bh & 15;
    const int qt = blockIdx.y;
    const int tid = threadIdx.x, lane = tid & 63, wid = tid >> 6;
    const int r = lane & 15, g = lane >> 4;

    __shared__ alignas(16) short Ks[64 * 64];   // K tile [tok][d], slot ^= row&7
    __shared__ alignas(16) short Vs[64 * 64];   // V^T tile [d][tok], slot ^= row&7
    __shared__ float mb[64];

    const int q0 = qt * 64 + wid * 16;
    const short* qbase = qrh + (size_t)(b * 1024 + q0 + r) * 1024 + h * 64;
    s16x8 qf0 = *(const s16x8*)(qbase + g * 8);        // B-frag: d = g*8+j
    s16x8 qf1 = *(const s16x8*)(qbase + 32 + g * 8);   // d = 32+g*8+j

    f32x4 z = {0.f, 0.f, 0.f, 0.f};
    f32x4 oacc[4];   // out^T: oacc[df][qi] = out[q=r][d = df*16 + g*4 + qi]
#pragma unroll
    for (int i = 0; i < 4; ++i) oacc[i] = z;
    float mrun = -1e30f, lrun = 0.f;

    const int srow = tid >> 2, sq = tid & 3;   // staging: 64 rows x 4 quarters
    const short* kg = kh + (size_t)(b * 1024 + srow) * 1024 + h * 64 + sq * 16;
    const short* vg = vT + ((size_t)(b * 16 + h)) * 65536 + (size_t)srow * 1024 + sq * 16;
    const int p0s = (sq * 2) ^ (srow & 7), p1s = (sq * 2 + 1) ^ (srow & 7);

    for (int t = 0; t < 16; ++t) {
        const int k0 = t * 64;
        if (t) __syncthreads();
        {   // stage K tile [64 tok][64 d], 16B slot s at row w -> s ^ (w&7)
            const short* kp = kg + (size_t)k0 * 1024;
            s16x8 k0v = *(const s16x8*)kp;
            s16x8 k1v = *(const s16x8*)(kp + 8);
            char* kb = (char*)Ks;
            *(s16x8*)(kb + srow * 128 + p0s * 16) = k0v;
            *(s16x8*)(kb + srow * 128 + p1s * 16) = k1v;
        }
        {   // stage V^T tile [64 d][64 tok], same swizzle
            const short* vp = vg + k0;
            s16x8 v0 = *(const s16x8*)vp;
            s16x8 v1 = *(const s16x8*)(vp + 8);
            char* vb = (char*)Vs;
            *(s16x8*)(vb + srow * 128 + p0s * 16) = v0;
            *(s16x8*)(vb + srow * 128 + p1s * 16) = v1;
        }
        if (tid < 64) mb[tid] = mask[b * 1024 + k0 + tid] ? -1e9f : 0.f;
        __syncthreads();

        // QK^T swapped: S^T[tok][q]; lane holds q=r, toks fn*16 + g*4 + qi
        float p[4][4];
        float tmax = -3e38f;
#pragma unroll
        for (int fn = 0; fn < 4; ++fn) {
            int row = fn * 16 + r;
            char* kb = (char*)Ks;
            s16x8 kfa = *(const s16x8*)(kb + row * 128 + ((g ^ (row & 7)) << 4));
            s16x8 kfb = *(const s16x8*)(kb + row * 128 + (((4 + g) ^ (row & 7)) << 4));
            f32x4 c = __builtin_amdgcn_mfma_f32_16x16x32_bf16(kfa, qf0, z, 0, 0, 0);
            c = __builtin_amdgcn_mfma_f32_16x16x32_bf16(kfb, qf1, c, 0, 0, 0);
            f32x4 mv = *(const f32x4*)&mb[fn * 16 + g * 4];
#pragma unroll
            for (int qi = 0; qi < 4; ++qi) {
                float s = c[qi] * 0.125f + mv[qi];
                p[fn][qi] = s;
                tmax = fmaxf(tmax, s);
            }
        }
        tmax = fmaxf(tmax, __shfl_xor(tmax, 16));
        tmax = fmaxf(tmax, __shfl_xor(tmax, 32));

        float mn = fmaxf(mrun, tmax);
        float corr = __expf(mrun - mn);
        mrun = mn;
        float tsum = 0.f;
#pragma unroll
        for (int fn = 0; fn < 4; ++fn)
#pragma unroll
            for (int qi = 0; qi < 4; ++qi) {
                float e = __expf(p[fn][qi] - mn);
                p[fn][qi] = e;
                tsum += e;
            }
        tsum += __shfl_xor(tsum, 16);
        tsum += __shfl_xor(tsum, 32);
        lrun = lrun * corr + tsum;
#pragma unroll
        for (int df = 0; df < 4; ++df)
#pragma unroll
            for (int qi = 0; qi < 4; ++qi) oacc[df][qi] *= corr;

        // PV: out^T += V^T * P^T.  k-mapping (shared by A and B):
        //   j=0..3 -> tok ks*32 + 4g + j ; j=4..7 -> tok ks*32 + 16 + 4g + (j-4)
#pragma unroll
        for (int ks = 0; ks < 2; ++ks) {
            s16x8 pb;
#pragma unroll
            for (int j = 0; j < 4; ++j) {
                pb[j]     = f2b(p[2 * ks][j]);
                pb[4 + j] = f2b(p[2 * ks + 1][j]);
            }
#pragma unroll
            for (int df = 0; df < 4; ++df) {
                int row = df * 16 + r;
                int sl0 = ks * 4 + (g >> 1), half = (g & 1) * 8;
                char* vb = (char*)Vs;
                s16x4 va0 = *(const s16x4*)(vb + row * 128 + ((sl0 ^ (row & 7)) << 4) + half);
                s16x4 va1 = *(const s16x4*)(vb + row * 128 + (((sl0 + 2) ^ (row & 7)) << 4) + half);
                s16x8 vf = {va0[0], va0[1], va0[2], va0[3], va1[0], va1[1], va1[2], va1[3]};
                oacc[df] = __builtin_amdgcn_mfma_f32_16x16x32_bf16(vf, pb, oacc[df], 0, 0, 0);
            }
        }
    }

    // epilogue: lane owns q = q0+r; d = df*16 + g*4 + qi (4 consecutive -> b64)
    float inv = 1.f / lrun;
#pragma unroll
    for (int df = 0; df < 4; ++df) {
        s16x4 o;
#pragma unroll
        for (int qi = 0; qi < 4; ++qi) o[qi] = f2b(oacc[df][qi] * inv);
        *(s16x4*)&outp[(size_t)(b * 1024 + q0 + r) * 1024 + h * 64 + df * 16 + g * 4] = o;
    }
}

// ---------------- launch ----------------
extern "C" void kernel_launch(void* const* d_in, const int* in_sizes, int n_in,
                              void* d_out, int out_size, void* d_ws, size_t ws_size,
                              hipStream_t stream) {
    const float* v  = (const float*)d_in[0];
    const float* k  = (const float*)d_in[1];
    const float* q  = (const float*)d_in[2];
    const float* rr = (const float*)d_in[3];
    const int* mask = (const int*)d_in[4];
    const float* Wv = (const float*)d_in[5];  const float* bv = (const float*)d_in[6];
    const float* Wk = (const float*)d_in[7];  const float* bk = (const float*)d_in[8];
    const float* Wq = (const float*)d_in[9];  const float* bq = (const float*)d_in[10];
    const float* Wr = (const float*)d_in[11]; const float* br = (const float*)d_in[12];
    const float* Wm = (const float*)d_in[13]; const float* bm = (const float*)d_in[14];

    const size_t NEED = 10485760u + 4u * 16777216u;   // 5 bf16 weights + 4 bf16 activations
    if (ws_size < NEED) return;                       // leaves poison -> visible failure

    char* ws = (char*)d_ws;
    short* Wb  = (short*)ws;                          // 5 x 1M bf16
    short* vtb = (short*)(ws + 10485760u);            // V^T [b][h][d][tok]
    short* khb = vtb + 8388608u;
    short* qrb = khb + 8388608u;
    short* att = qrb + 8388608u;

    Ptr5 p5;
    p5.p[0] = Wv; p5.p[1] = Wk; p5.p[2] = Wq; p5.p[3] = Wr; p5.p[4] = Wm;
    cvtW<<<dim3(512, 5), 256, 0, stream>>>(p5, Wb);

    dim3 gg(8, 64);   // N/128, M/128
    gemm_nt<1, 2, 0><<<gg, 256, 0, stream>>>(v,  nullptr, Wb,                 nullptr,            bv, nullptr, vtb);
    gemm_nt<1, 0, 0><<<gg, 256, 0, stream>>>(k,  nullptr, Wb + 1048576u,      nullptr,            bk, nullptr, khb);
    gemm_nt<1, 0, 1><<<gg, 256, 0, stream>>>(q,  rr,      Wb + 2u * 1048576u, Wb + 3u * 1048576u, bq, br,     qrb);

    attn_fwd<<<dim3(128, 16), 256, 0, stream>>>(qrb, khb, vtb, mask, att);

    gemm_nt<0, 1, 0><<<gg, 256, 0, stream>>>(att, nullptr, Wb + 4u * 1048576u, nullptr, bm, nullptr, (float*)d_out);
}

// Round 3
// 261.132 us; speedup vs baseline: 1.3632x; 1.1540x over previous
//
#include <hip/hip_runtime.h>
#include <hip/hip_bf16.h>
#include <stdint.h>

typedef __attribute__((ext_vector_type(4))) float f32x4;
typedef __attribute__((ext_vector_type(8))) short s16x8;
typedef __attribute__((ext_vector_type(4))) short s16x4;

typedef const __attribute__((address_space(1))) unsigned glb_u32;
typedef __attribute__((address_space(3))) unsigned lds_u32;

#define DEVI __device__ __forceinline__

DEVI short f2b(float f) {
    union { float f; unsigned u; } v; v.f = f;
    unsigned r = v.u + 0x7fffu + ((v.u >> 16) & 1u);
    return (short)(r >> 16);
}

// ---------------- converts: f32 -> bf16 ----------------
struct Ptr5 { const float* p[5]; };
struct Ptr4 { const float* p[4]; };

__global__ __launch_bounds__(256) void cvtW(Ptr5 src, short* __restrict__ dst) {
    const float* s = src.p[blockIdx.y];
    short* d = dst + (size_t)blockIdx.y * (1024u * 1024u);
    int i = (blockIdx.x * 256 + threadIdx.x) * 8;
    f32x4 a = *(const f32x4*)(s + i);
    f32x4 b = *(const f32x4*)(s + i + 4);
    s16x8 o;
#pragma unroll
    for (int j = 0; j < 4; ++j) { o[j] = f2b(a[j]); o[4 + j] = f2b(b[j]); }
    *(s16x8*)(d + i) = o;
}

__global__ __launch_bounds__(256) void cvtA(Ptr4 src, short* __restrict__ dst) {
    const float* s = src.p[blockIdx.y];
    short* d = dst + (size_t)blockIdx.y * (8u * 1024u * 1024u);
    int i = (blockIdx.x * 256 + threadIdx.x) * 8;
    f32x4 a = *(const f32x4*)(s + i);
    f32x4 b = *(const f32x4*)(s + i + 4);
    s16x8 o;
#pragma unroll
    for (int j = 0; j < 4; ++j) { o[j] = f2b(a[j]); o[4 + j] = f2b(b[j]); }
    *(s16x8*)(d + i) = o;
}

// ---------------- NT GEMM: C[M=8192][N=1024] = A[M][K] * W[N][K]^T + bias ----
// AF32: A is f32 (reg-staged with convert); else bf16 via global_load_lds.
// OUTMODE: 0 = bf16 row-major, 1 = f32 row-major, 2 = bf16 per-head-transposed
//          [b][h][d][tok] (for attention V).
// TWO: C = A0*W0^T + A1*W1^T + b0 + b1 (K=2*1024).
template<int AF32, int OUTMODE, int TWO>
__global__ __launch_bounds__(256) void gemm_nt(
    const void* __restrict__ A0_, const void* __restrict__ A1_,
    const short* __restrict__ W0, const short* __restrict__ W1,
    const float* __restrict__ b0, const float* __restrict__ b1,
    void* __restrict__ C_)
{
    constexpr int K = 1024, N = 1024;
    const int tid = threadIdx.x;
    const int lane = tid & 63, wid = tid >> 6;
    const int wm = wid >> 1, wn = wid & 1;
    const int r = lane & 15, g = lane >> 4;

    // XCD-chunked bijective swizzle: 512 blocks, XCD p%8 owns logical [64p%8, ...)
    const int bid = blockIdx.x;
    const int logical = (bid & 7) * 64 + (bid >> 3);
    const int n0 = (logical & 7) * 128, m0 = (logical >> 3) * 128;

    __shared__ alignas(16) short As[2][128 * 32];   // linear [row][32]
    __shared__ alignas(16) short Ws[2][128 * 32];

    // ---- staging (bf16 path): global_load_lds, wave-uniform dest + lane*16B
    auto stage_async = [&](int buf, int kt) {
        int kk = kt * 32;
        const short* Ap = (const short*)A0_; const short* Wp = W0;
        if (TWO && kk >= 1024) { Ap = (const short*)A1_; Wp = W1; kk &= 1023; }
#pragma unroll
        for (int i = 0; i < 2; ++i) {
            int row = wid * 32 + i * 16 + (lane >> 2);
            const short* ga = Ap + (size_t)(m0 + row) * K + kk + (lane & 3) * 8;
            const short* gw = Wp + (size_t)(n0 + row) * K + kk + (lane & 3) * 8;
            __builtin_amdgcn_global_load_lds((glb_u32*)ga,
                (lds_u32*)&As[buf][(wid * 32 + i * 16) * 32], 16, 0, 0);
            __builtin_amdgcn_global_load_lds((glb_u32*)gw,
                (lds_u32*)&Ws[buf][(wid * 32 + i * 16) * 32], 16, 0, 0);
        }
    };

    // ---- staging (f32 path): reg load + convert + linear LDS write
    const int srow = tid >> 1, shalf = tid & 1;
    f32x4 a0g, a1g, a2g, a3g;
    s16x8 wg0, wg1;
    auto load_regs = [&](int kt) {
        int kk = kt * 32;
        const short* wp = W0 + (size_t)(n0 + srow) * K + kk + shalf * 16;
        wg0 = *(const s16x8*)wp;
        wg1 = *(const s16x8*)(wp + 8);
        const float* ap = (const float*)A0_ + (size_t)(m0 + srow) * K + kk + shalf * 16;
        a0g = *(const f32x4*)ap;       a1g = *(const f32x4*)(ap + 4);
        a2g = *(const f32x4*)(ap + 8); a3g = *(const f32x4*)(ap + 12);
    };
    auto store_lds = [&](int buf) {
        s16x8 s0, s1;
#pragma unroll
        for (int j = 0; j < 4; ++j) {
            s0[j] = f2b(a0g[j]); s0[4 + j] = f2b(a1g[j]);
            s1[j] = f2b(a2g[j]); s1[4 + j] = f2b(a3g[j]);
        }
        char* ab = (char*)As[buf];
        *(s16x8*)(ab + srow * 64 + shalf * 32) = s0;
        *(s16x8*)(ab + srow * 64 + shalf * 32 + 16) = s1;
        char* wb = (char*)Ws[buf];
        *(s16x8*)(wb + srow * 64 + shalf * 32) = wg0;
        *(s16x8*)(wb + srow * 64 + shalf * 32 + 16) = wg1;
    };

    f32x4 z = {0.f, 0.f, 0.f, 0.f};
    f32x4 acc[4][4];
#pragma unroll
    for (int i = 0; i < 4; ++i)
#pragma unroll
        for (int j = 0; j < 4; ++j) acc[i][j] = z;

    auto compute = [&](int buf) {
        s16x8 af[4], bfr[4];
#pragma unroll
        for (int f = 0; f < 4; ++f) {
            af[f]  = *(const s16x8*)&As[buf][(wm * 64 + f * 16 + r) * 32 + g * 8];
            bfr[f] = *(const s16x8*)&Ws[buf][(wn * 64 + f * 16 + r) * 32 + g * 8];
        }
#pragma unroll
        for (int i = 0; i < 4; ++i)
#pragma unroll
            for (int j = 0; j < 4; ++j)
                acc[i][j] = __builtin_amdgcn_mfma_f32_16x16x32_bf16(af[i], bfr[j], acc[i][j], 0, 0, 0);
    };

    constexpr int NK = TWO ? 64 : 32;
    if constexpr (AF32) { load_regs(0); store_lds(0); }
    else stage_async(0, 0);
    __syncthreads();
    int buf = 0;
    for (int kt = 0; kt < NK; ++kt) {
        if (kt + 1 < NK) {
            if constexpr (AF32) load_regs(kt + 1);
            else stage_async(buf ^ 1, kt + 1);
        }
        compute(buf);
        if (AF32 && kt + 1 < NK) store_lds(buf ^ 1);
        __syncthreads();
        buf ^= 1;
    }

    // epilogue: C layout col=lane&15, row=(lane>>4)*4+reg
#pragma unroll
    for (int j = 0; j < 4; ++j) {
        int col = n0 + wn * 64 + j * 16 + r;
        float bb = b0[col];
        if (TWO) bb += b1[col];
#pragma unroll
        for (int i = 0; i < 4; ++i) {
            int rowb = m0 + wm * 64 + i * 16 + g * 4;
            if constexpr (OUTMODE == 2) {
                // V^T per head: [b][h][d][tok]; 4 consecutive toks -> one b64 store
                int bb_ = rowb >> 10, tok = rowb & 1023;
                short* dst = (short*)C_ + ((size_t)(bb_ * 16 + (col >> 6))) * 65536
                           + (size_t)(col & 63) * 1024 + tok;
                s16x4 o;
#pragma unroll
                for (int q = 0; q < 4; ++q) o[q] = f2b(acc[i][j][q] + bb);
                *(s16x4*)dst = o;
            } else {
#pragma unroll
                for (int q = 0; q < 4; ++q) {
                    float val = acc[i][j][q] + bb;
                    if constexpr (OUTMODE == 1)
                        ((float*)C_)[(size_t)(rowb + q) * N + col] = val;
                    else
                        ((short*)C_)[(size_t)(rowb + q) * N + col] = f2b(val);
                }
            }
        }
    }
}

// ---------------- flash attention (swapped QK^T, in-register softmax) --------
__global__ __launch_bounds__(256) void attn_fwd(
    const short* __restrict__ qrh, const short* __restrict__ kh,
    const short* __restrict__ vT, const int* __restrict__ mask,
    short* __restrict__ outp)
{
    const int bh = blockIdx.x;
    const int b = bh >> 4, h = bh & 15;
    const int qt = blockIdx.y;
    const int tid = threadIdx.x, lane = tid & 63, wid = tid >> 6;
    const int r = lane & 15, g = lane >> 4;

    __shared__ alignas(16) short Ks[64 * 64];   // K tile [tok][d], slot ^= row&7
    __shared__ alignas(16) short Vs[64 * 64];   // V^T tile [d][tok], slot ^= row&7
    __shared__ alignas(16) float mb[64];

    const int q0 = qt * 64 + wid * 16;
    const short* qbase = qrh + (size_t)(b * 1024 + q0 + r) * 1024 + h * 64;
    s16x8 qf0 = *(const s16x8*)(qbase + g * 8);
    s16x8 qf1 = *(const s16x8*)(qbase + 32 + g * 8);

    f32x4 z = {0.f, 0.f, 0.f, 0.f};
    f32x4 oacc[4];
#pragma unroll
    for (int i = 0; i < 4; ++i) oacc[i] = z;
    float mrun = -1e30f, lrun = 0.f;

    const int srow = tid >> 2, sq = tid & 3;
    const short* kg = kh + (size_t)(b * 1024 + srow) * 1024 + h * 64 + sq * 16;
    const short* vg = vT + ((size_t)(b * 16 + h)) * 65536 + (size_t)srow * 1024 + sq * 16;
    const int p0s = (sq * 2) ^ (srow & 7), p1s = (sq * 2 + 1) ^ (srow & 7);

    for (int t = 0; t < 16; ++t) {
        const int k0 = t * 64;
        if (t) __syncthreads();
        {
            const short* kp = kg + (size_t)k0 * 1024;
            s16x8 k0v = *(const s16x8*)kp;
            s16x8 k1v = *(const s16x8*)(kp + 8);
            char* kb = (char*)Ks;
            *(s16x8*)(kb + srow * 128 + p0s * 16) = k0v;
            *(s16x8*)(kb + srow * 128 + p1s * 16) = k1v;
        }
        {
            const short* vp = vg + k0;
            s16x8 v0 = *(const s16x8*)vp;
            s16x8 v1 = *(const s16x8*)(vp + 8);
            char* vb = (char*)Vs;
            *(s16x8*)(vb + srow * 128 + p0s * 16) = v0;
            *(s16x8*)(vb + srow * 128 + p1s * 16) = v1;
        }
        if (tid < 64) mb[tid] = mask[b * 1024 + k0 + tid] ? -1e9f : 0.f;
        __syncthreads();

        float p[4][4];
        float tmax = -3e38f;
#pragma unroll
        for (int fn = 0; fn < 4; ++fn) {
            int row = fn * 16 + r;
            char* kb = (char*)Ks;
            s16x8 kfa = *(const s16x8*)(kb + row * 128 + ((g ^ (row & 7)) << 4));
            s16x8 kfb = *(const s16x8*)(kb + row * 128 + (((4 + g) ^ (row & 7)) << 4));
            f32x4 c = __builtin_amdgcn_mfma_f32_16x16x32_bf16(kfa, qf0, z, 0, 0, 0);
            c = __builtin_amdgcn_mfma_f32_16x16x32_bf16(kfb, qf1, c, 0, 0, 0);
            f32x4 mv = *(const f32x4*)&mb[fn * 16 + g * 4];
#pragma unroll
            for (int qi = 0; qi < 4; ++qi) {
                float s = c[qi] * 0.125f + mv[qi];
                p[fn][qi] = s;
                tmax = fmaxf(tmax, s);
            }
        }
        tmax = fmaxf(tmax, __shfl_xor(tmax, 16));
        tmax = fmaxf(tmax, __shfl_xor(tmax, 32));

        float mn = fmaxf(mrun, tmax);
        float corr = __expf(mrun - mn);
        mrun = mn;
        float tsum = 0.f;
#pragma unroll
        for (int fn = 0; fn < 4; ++fn)
#pragma unroll
            for (int qi = 0; qi < 4; ++qi) {
                float e = __expf(p[fn][qi] - mn);
                p[fn][qi] = e;
                tsum += e;
            }
        tsum += __shfl_xor(tsum, 16);
        tsum += __shfl_xor(tsum, 32);
        lrun = lrun * corr + tsum;
#pragma unroll
        for (int df = 0; df < 4; ++df)
#pragma unroll
            for (int qi = 0; qi < 4; ++qi) oacc[df][qi] *= corr;

#pragma unroll
        for (int ks = 0; ks < 2; ++ks) {
            s16x8 pb;
#pragma unroll
            for (int j = 0; j < 4; ++j) {
                pb[j]     = f2b(p[2 * ks][j]);
                pb[4 + j] = f2b(p[2 * ks + 1][j]);
            }
#pragma unroll
            for (int df = 0; df < 4; ++df) {
                int row = df * 16 + r;
                int sl0 = ks * 4 + (g >> 1), half = (g & 1) * 8;
                char* vb = (char*)Vs;
                s16x4 va0 = *(const s16x4*)(vb + row * 128 + ((sl0 ^ (row & 7)) << 4) + half);
                s16x4 va1 = *(const s16x4*)(vb + row * 128 + (((sl0 + 2) ^ (row & 7)) << 4) + half);
                s16x8 vf = {va0[0], va0[1], va0[2], va0[3], va1[0], va1[1], va1[2], va1[3]};
                oacc[df] = __builtin_amdgcn_mfma_f32_16x16x32_bf16(vf, pb, oacc[df], 0, 0, 0);
            }
        }
    }

    float inv = 1.f / lrun;
#pragma unroll
    for (int df = 0; df < 4; ++df) {
        s16x4 o;
#pragma unroll
        for (int qi = 0; qi < 4; ++qi) o[qi] = f2b(oacc[df][qi] * inv);
        *(s16x4*)&outp[(size_t)(b * 1024 + q0 + r) * 1024 + h * 64 + df * 16 + g * 4] = o;
    }
}

// ---------------- launch ----------------
extern "C" void kernel_launch(void* const* d_in, const int* in_sizes, int n_in,
                              void* d_out, int out_size, void* d_ws, size_t ws_size,
                              hipStream_t stream) {
    const float* v  = (const float*)d_in[0];
    const float* k  = (const float*)d_in[1];
    const float* q  = (const float*)d_in[2];
    const float* rr = (const float*)d_in[3];
    const int* mask = (const int*)d_in[4];
    const float* Wv = (const float*)d_in[5];  const float* bv = (const float*)d_in[6];
    const float* Wk = (const float*)d_in[7];  const float* bk = (const float*)d_in[8];
    const float* Wq = (const float*)d_in[9];  const float* bq = (const float*)d_in[10];
    const float* Wr = (const float*)d_in[11]; const float* br = (const float*)d_in[12];
    const float* Wm = (const float*)d_in[13]; const float* bm = (const float*)d_in[14];

    const size_t MB = 1048576u;
    const size_t NEED_FULL = 90u * MB;   // W 10 + 4 bf16 acts 64 + 1 fresh 16 (rest recycled)
    const size_t NEED_B    = 74u * MB;   // v stays f32
    char* ws = (char*)d_ws;
    short* Wb = (short*)ws;              // 5 x 1M bf16

    Ptr5 p5;
    p5.p[0] = Wv; p5.p[1] = Wk; p5.p[2] = Wq; p5.p[3] = Wr; p5.p[4] = Wm;
    cvtW<<<dim3(512, 5), 256, 0, stream>>>(p5, Wb);

    const short* Wvb = Wb, *Wkb = Wb + 1048576u, *Wqb = Wb + 2097152u,
               *Wrb = Wb + 3145728u, *Wmb = Wb + 4194304u;
    dim3 gg(512);

    if (ws_size >= NEED_FULL) {
        short* vb  = (short*)(ws + 10u * MB);
        short* kb  = vb + 8388608u;
        short* qb  = kb + 8388608u;
        short* rb  = qb + 8388608u;
        short* vtb = rb + 8388608u;          // fresh, 74..90 MB
        short* khb = vb;                     // after v-proj, vb dead
        short* qrb = kb;                     // after k-proj, kb dead
        short* att = qb;                     // after qr-proj, qb dead

        Ptr4 p4; p4.p[0] = v; p4.p[1] = k; p4.p[2] = q; p4.p[3] = rr;
        cvtA<<<dim3(4096, 4), 256, 0, stream>>>(p4, vb);

        gemm_nt<0, 2, 0><<<gg, 256, 0, stream>>>(vb, nullptr, Wvb, nullptr, bv, nullptr, vtb);
        gemm_nt<0, 0, 0><<<gg, 256, 0, stream>>>(kb, nullptr, Wkb, nullptr, bk, nullptr, khb);
        gemm_nt<0, 0, 1><<<gg, 256, 0, stream>>>(qb, rb, Wqb, Wrb, bq, br, qrb);
        attn_fwd<<<dim3(128, 16), 256, 0, stream>>>(qrb, khb, vtb, mask, att);
        gemm_nt<0, 1, 0><<<gg, 256, 0, stream>>>(att, nullptr, Wmb, nullptr, bm, nullptr, (float*)d_out);
    } else if (ws_size >= NEED_B) {
        short* kb  = (short*)(ws + 10u * MB);
        short* qb  = kb + 8388608u;
        short* rb  = qb + 8388608u;
        short* qrb = rb + 8388608u;          // fresh, 58..74 MB
        short* vtb = qb;                     // after qr-proj, qb dead
        short* khb = rb;                     // after qr-proj, rb dead
        short* att = kb;                     // after k-proj, kb dead

        Ptr4 p4; p4.p[0] = k; p4.p[1] = q; p4.p[2] = rr; p4.p[3] = k;  // [3] unused pad
        cvtA<<<dim3(4096, 3), 256, 0, stream>>>(p4, kb);

        gemm_nt<0, 0, 1><<<gg, 256, 0, stream>>>(qb, rb, Wqb, Wrb, bq, br, qrb);
        gemm_nt<1, 2, 0><<<gg, 256, 0, stream>>>(v, nullptr, Wvb, nullptr, bv, nullptr, vtb);
        gemm_nt<0, 0, 0><<<gg, 256, 0, stream>>>(kb, nullptr, Wkb, nullptr, bk, nullptr, khb);
        attn_fwd<<<dim3(128, 16), 256, 0, stream>>>(qrb, khb, vtb, mask, att);
        gemm_nt<0, 1, 0><<<gg, 256, 0, stream>>>(att, nullptr, Wmb, nullptr, bm, nullptr, (float*)d_out);
    }
    // else: insufficient ws -> leave poison (visible failure)
}

// Round 5
// 253.333 us; speedup vs baseline: 1.4052x; 1.0308x over previous
//
#include <hip/hip_runtime.h>
#include <hip/hip_bf16.h>
#include <stdint.h>

typedef __attribute__((ext_vector_type(4))) float f32x4;
typedef __attribute__((ext_vector_type(8))) short s16x8;
typedef __attribute__((ext_vector_type(4))) short s16x4;
typedef __attribute__((ext_vector_type(4))) int i32x4;

typedef const __attribute__((address_space(1))) unsigned glb_u32;
typedef __attribute__((address_space(3))) unsigned lds_u32;

#define DEVI __device__ __forceinline__

DEVI short f2b(float f) {
    union { float f; unsigned u; } v; v.f = f;
    unsigned r = v.u + 0x7fffu + ((v.u >> 16) & 1u);
    return (short)(r >> 16);
}

// ---------------- converts: f32 -> bf16 ----------------
struct Ptr5 { const float* p[5]; };
struct Ptr4 { const float* p[4]; };

__global__ __launch_bounds__(256) void cvtW(Ptr5 src, short* __restrict__ dst) {
    const float* s = src.p[blockIdx.y];
    short* d = dst + (size_t)blockIdx.y * (1024u * 1024u);
    int i = (blockIdx.x * 256 + threadIdx.x) * 8;
    f32x4 a = *(const f32x4*)(s + i);
    f32x4 b = *(const f32x4*)(s + i + 4);
    s16x8 o;
#pragma unroll
    for (int j = 0; j < 4; ++j) { o[j] = f2b(a[j]); o[4 + j] = f2b(b[j]); }
    *(s16x8*)(d + i) = o;
}

__global__ __launch_bounds__(256) void cvtA(Ptr4 src, short* __restrict__ dst) {
    const float* s = src.p[blockIdx.y];
    short* d = dst + (size_t)blockIdx.y * (8u * 1024u * 1024u);
    int i = (blockIdx.x * 256 + threadIdx.x) * 8;
    f32x4 a = *(const f32x4*)(s + i);
    f32x4 b = *(const f32x4*)(s + i + 4);
    s16x8 o;
#pragma unroll
    for (int j = 0; j < 4; ++j) { o[j] = f2b(a[j]); o[4 + j] = f2b(b[j]); }
    *(s16x8*)(d + i) = o;
}

// ---------------- NT GEMM: C[M=8192][N=1024] = A[M][K] * W[N][K]^T + bias ----
// AF32: A is f32 (reg-staged with convert); else bf16 via global_load_lds.
// OUTMODE: 0 = bf16 row-major, 1 = f32 row-major, 2 = bf16 per-head-transposed
//          [b][h][d][tok] (for attention V).
// TWO: C = A0*W0^T + A1*W1^T + b0 + b1 (K=2*1024).
template<int AF32, int OUTMODE, int TWO>
__global__ __launch_bounds__(256) void gemm_nt(
    const void* __restrict__ A0_, const void* __restrict__ A1_,
    const short* __restrict__ W0, const short* __restrict__ W1,
    const float* __restrict__ b0, const float* __restrict__ b1,
    void* __restrict__ C_)
{
    constexpr int K = 1024, N = 1024;
    const int tid = threadIdx.x;
    const int lane = tid & 63, wid = tid >> 6;
    const int wm = wid >> 1, wn = wid & 1;
    const int r = lane & 15, g = lane >> 4;

    // XCD-chunked bijective swizzle: 512 blocks, XCD p%8 owns logical [64p%8, ...)
    const int bid = blockIdx.x;
    const int logical = (bid & 7) * 64 + (bid >> 3);
    const int n0 = (logical & 7) * 128, m0 = (logical >> 3) * 128;

    __shared__ alignas(16) short As[2][128 * 32];   // linear [row][32]
    __shared__ alignas(16) short Ws[2][128 * 32];

    auto stage_async = [&](int buf, int kt) {
        int kk = kt * 32;
        const short* Ap = (const short*)A0_; const short* Wp = W0;
        if (TWO && kk >= 1024) { Ap = (const short*)A1_; Wp = W1; kk &= 1023; }
#pragma unroll
        for (int i = 0; i < 2; ++i) {
            int row = wid * 32 + i * 16 + (lane >> 2);
            const short* ga = Ap + (size_t)(m0 + row) * K + kk + (lane & 3) * 8;
            const short* gw = Wp + (size_t)(n0 + row) * K + kk + (lane & 3) * 8;
            __builtin_amdgcn_global_load_lds((glb_u32*)ga,
                (lds_u32*)&As[buf][(wid * 32 + i * 16) * 32], 16, 0, 0);
            __builtin_amdgcn_global_load_lds((glb_u32*)gw,
                (lds_u32*)&Ws[buf][(wid * 32 + i * 16) * 32], 16, 0, 0);
        }
    };

    const int srow = tid >> 1, shalf = tid & 1;
    f32x4 a0g, a1g, a2g, a3g;
    s16x8 wg0, wg1;
    auto load_regs = [&](int kt) {
        int kk = kt * 32;
        const short* wp = W0 + (size_t)(n0 + srow) * K + kk + shalf * 16;
        wg0 = *(const s16x8*)wp;
        wg1 = *(const s16x8*)(wp + 8);
        const float* ap = (const float*)A0_ + (size_t)(m0 + srow) * K + kk + shalf * 16;
        a0g = *(const f32x4*)ap;       a1g = *(const f32x4*)(ap + 4);
        a2g = *(const f32x4*)(ap + 8); a3g = *(const f32x4*)(ap + 12);
    };
    auto store_lds = [&](int buf) {
        s16x8 s0, s1;
#pragma unroll
        for (int j = 0; j < 4; ++j) {
            s0[j] = f2b(a0g[j]); s0[4 + j] = f2b(a1g[j]);
            s1[j] = f2b(a2g[j]); s1[4 + j] = f2b(a3g[j]);
        }
        char* ab = (char*)As[buf];
        *(s16x8*)(ab + srow * 64 + shalf * 32) = s0;
        *(s16x8*)(ab + srow * 64 + shalf * 32 + 16) = s1;
        char* wb = (char*)Ws[buf];
        *(s16x8*)(wb + srow * 64 + shalf * 32) = wg0;
        *(s16x8*)(wb + srow * 64 + shalf * 32 + 16) = wg1;
    };

    f32x4 z = {0.f, 0.f, 0.f, 0.f};
    f32x4 acc[4][4];
#pragma unroll
    for (int i = 0; i < 4; ++i)
#pragma unroll
        for (int j = 0; j < 4; ++j) acc[i][j] = z;

    auto compute = [&](int buf) {
        s16x8 af[4], bfr[4];
#pragma unroll
        for (int f = 0; f < 4; ++f) {
            af[f]  = *(const s16x8*)&As[buf][(wm * 64 + f * 16 + r) * 32 + g * 8];
            bfr[f] = *(const s16x8*)&Ws[buf][(wn * 64 + f * 16 + r) * 32 + g * 8];
        }
#pragma unroll
        for (int i = 0; i < 4; ++i)
#pragma unroll
            for (int j = 0; j < 4; ++j)
                acc[i][j] = __builtin_amdgcn_mfma_f32_16x16x32_bf16(af[i], bfr[j], acc[i][j], 0, 0, 0);
    };

    constexpr int NK = TWO ? 64 : 32;
    if constexpr (AF32) { load_regs(0); store_lds(0); }
    else stage_async(0, 0);
    __syncthreads();
    int buf = 0;
    for (int kt = 0; kt < NK; ++kt) {
        if (kt + 1 < NK) {
            if constexpr (AF32) load_regs(kt + 1);
            else stage_async(buf ^ 1, kt + 1);
        }
        compute(buf);
        if (AF32 && kt + 1 < NK) store_lds(buf ^ 1);
        __syncthreads();
        buf ^= 1;
    }

    // epilogue: C layout col=lane&15, row=(lane>>4)*4+reg
#pragma unroll
    for (int j = 0; j < 4; ++j) {
        int col = n0 + wn * 64 + j * 16 + r;
        float bb = b0[col];
        if (TWO) bb += b1[col];
#pragma unroll
        for (int i = 0; i < 4; ++i) {
            int rowb = m0 + wm * 64 + i * 16 + g * 4;
            if constexpr (OUTMODE == 2) {
                // V^T per head: [b][h][d][tok]; 4 consecutive toks -> one b64 store
                int bb_ = rowb >> 10, tok = rowb & 1023;
                short* dst = (short*)C_ + ((size_t)(bb_ * 16 + (col >> 6))) * 65536
                           + (size_t)(col & 63) * 1024 + tok;
                s16x4 o;
#pragma unroll
                for (int q = 0; q < 4; ++q) o[q] = f2b(acc[i][j][q] + bb);
                *(s16x4*)dst = o;
            } else {
#pragma unroll
                for (int q = 0; q < 4; ++q) {
                    float val = acc[i][j][q] + bb;
                    if constexpr (OUTMODE == 1)
                        ((float*)C_)[(size_t)(rowb + q) * N + col] = val;
                    else
                        ((short*)C_)[(size_t)(rowb + q) * N + col] = f2b(val);
                }
            }
        }
    }
}

// ---------------- flash attention v3 (round-3 math + dual q-group + T14) ----
// grid (128 bh, 8 qt); block 256 = 4 waves; wave handles 32 q-rows (2 groups
// of 16 sharing every K/V fragment read). Swapped QK^T, in-register softmax,
// always-rescale (round-3 verified), PV via b64-pair V reads (round-3 verified).
__global__ __launch_bounds__(256) void attn_fwd(
    const short* __restrict__ qrh, const short* __restrict__ kh,
    const short* __restrict__ vT, const int* __restrict__ mask,
    short* __restrict__ outp)
{
    const int bh = blockIdx.x;
    const int b = bh >> 4, h = bh & 15;
    const int qt = blockIdx.y;
    const int tid = threadIdx.x, lane = tid & 63, wid = tid >> 6;
    const int r = lane & 15, g = lane >> 4;

    __shared__ alignas(16) short Ks[64 * 64];   // [tok][d], 16B slot ^= row&7
    __shared__ alignas(16) short Vs[64 * 64];   // [d][tok], same swizzle
    __shared__ alignas(16) float mb[1024];      // pre-scaled mask, whole row

    {   // premask: mask[b][tok] ? -1e9 : 0
        i32x4 mi = *(const i32x4*)(mask + b * 1024 + tid * 4);
        f32x4 mv;
#pragma unroll
        for (int j = 0; j < 4; ++j) mv[j] = mi[j] ? -1e9f : 0.f;
        *(f32x4*)&mb[tid * 4] = mv;
    }

    const int q0 = qt * 128 + wid * 32;
    const short* qbA = qrh + (size_t)(b * 1024 + q0 + r) * 1024 + h * 64;
    const short* qbB = qbA + 16 * 1024;
    s16x8 qA0 = *(const s16x8*)(qbA + g * 8);
    s16x8 qA1 = *(const s16x8*)(qbA + 32 + g * 8);
    s16x8 qB0 = *(const s16x8*)(qbB + g * 8);
    s16x8 qB1 = *(const s16x8*)(qbB + 32 + g * 8);

    f32x4 z = {0.f, 0.f, 0.f, 0.f};
    f32x4 oA[4], oB[4];
#pragma unroll
    for (int i = 0; i < 4; ++i) { oA[i] = z; oB[i] = z; }
    float mA = -1e30f, mB = -1e30f, lA = 0.f, lB = 0.f;

    // staging: thread (srow, sq) covers row srow, 16 elems at sq*16
    const int srow = tid >> 2, sq = tid & 3;
    const short* kg = kh + (size_t)(b * 1024 + srow) * 1024 + h * 64 + sq * 16;
    const short* vg = vT + ((size_t)(b * 16 + h)) * 65536 + (size_t)srow * 1024 + sq * 16;
    const int p0s = (sq * 2) ^ (srow & 7), p1s = (sq * 2 + 1) ^ (srow & 7);

    s16x8 kr0, kr1, vr0, vr1;
    auto stage_load = [&](int t) {
        const short* kp = kg + (size_t)(t * 64) * 1024;
        kr0 = *(const s16x8*)kp; kr1 = *(const s16x8*)(kp + 8);
        const short* vp = vg + t * 64;
        vr0 = *(const s16x8*)vp; vr1 = *(const s16x8*)(vp + 8);
    };
    auto stage_write = [&]() {
        char* kb2 = (char*)Ks;
        *(s16x8*)(kb2 + srow * 128 + p0s * 16) = kr0;
        *(s16x8*)(kb2 + srow * 128 + p1s * 16) = kr1;
        char* vb2 = (char*)Vs;
        *(s16x8*)(vb2 + srow * 128 + p0s * 16) = vr0;
        *(s16x8*)(vb2 + srow * 128 + p1s * 16) = vr1;
    };

    stage_load(0);
    for (int t = 0; t < 16; ++t) {
        if (t) __syncthreads();
        stage_write();
        __syncthreads();
        if (t < 15) stage_load(t + 1);   // T14: issue next tile loads early

        // QK^T swapped: lane holds q=r (grpA) / q=16+r (grpB), toks fn*16+g*4+qi
        f32x4 pA[4], pB[4];
        float tmA = -3e38f, tmB = -3e38f;
        char* kb2 = (char*)Ks;
#pragma unroll
        for (int fn = 0; fn < 4; ++fn) {
            int row = fn * 16 + r;
            s16x8 kfa = *(const s16x8*)(kb2 + row * 128 + ((g ^ (row & 7)) << 4));
            s16x8 kfb = *(const s16x8*)(kb2 + row * 128 + (((4 + g) ^ (row & 7)) << 4));
            f32x4 cA = __builtin_amdgcn_mfma_f32_16x16x32_bf16(kfa, qA0, z, 0, 0, 0);
            cA = __builtin_amdgcn_mfma_f32_16x16x32_bf16(kfb, qA1, cA, 0, 0, 0);
            f32x4 cB = __builtin_amdgcn_mfma_f32_16x16x32_bf16(kfa, qB0, z, 0, 0, 0);
            cB = __builtin_amdgcn_mfma_f32_16x16x32_bf16(kfb, qB1, cB, 0, 0, 0);
            f32x4 mv = *(const f32x4*)&mb[t * 64 + fn * 16 + g * 4];
#pragma unroll
            for (int qi = 0; qi < 4; ++qi) {
                float sA = cA[qi] * 0.125f + mv[qi];
                float sB = cB[qi] * 0.125f + mv[qi];
                pA[fn][qi] = sA; pB[fn][qi] = sB;
                tmA = fmaxf(tmA, sA); tmB = fmaxf(tmB, sB);
            }
        }
        tmA = fmaxf(tmA, __shfl_xor(tmA, 16)); tmA = fmaxf(tmA, __shfl_xor(tmA, 32));
        tmB = fmaxf(tmB, __shfl_xor(tmB, 16)); tmB = fmaxf(tmB, __shfl_xor(tmB, 32));

        // online softmax, unconditional rescale (round-3 verified)
        float mnA = fmaxf(mA, tmA), mnB = fmaxf(mB, tmB);
        float cA_ = __expf(mA - mnA), cB_ = __expf(mB - mnB);
        mA = mnA; mB = mnB;
        float tsA = 0.f, tsB = 0.f;
#pragma unroll
        for (int fn = 0; fn < 4; ++fn)
#pragma unroll
            for (int qi = 0; qi < 4; ++qi) {
                float eA = __expf(pA[fn][qi] - mA); pA[fn][qi] = eA; tsA += eA;
                float eB = __expf(pB[fn][qi] - mB); pB[fn][qi] = eB; tsB += eB;
            }
        tsA += __shfl_xor(tsA, 16); tsA += __shfl_xor(tsA, 32);
        tsB += __shfl_xor(tsB, 16); tsB += __shfl_xor(tsB, 32);
        lA = lA * cA_ + tsA; lB = lB * cB_ + tsB;
#pragma unroll
        for (int df = 0; df < 4; ++df)
#pragma unroll
            for (int qi = 0; qi < 4; ++qi) { oA[df][qi] *= cA_; oB[df][qi] *= cB_; }

        // PV: round-3 b64-pair V reads; k-mapping (g,j) -> tok ks*32+(j>=4)*16+g*4+(j&3)
        char* vb2 = (char*)Vs;
#pragma unroll
        for (int ks = 0; ks < 2; ++ks) {
            s16x8 pbA, pbB;
#pragma unroll
            for (int j = 0; j < 4; ++j) {
                pbA[j]     = f2b(pA[2 * ks][j]);
                pbA[4 + j] = f2b(pA[2 * ks + 1][j]);
                pbB[j]     = f2b(pB[2 * ks][j]);
                pbB[4 + j] = f2b(pB[2 * ks + 1][j]);
            }
#pragma unroll
            for (int df = 0; df < 4; ++df) {
                int row = df * 16 + r;
                int sl0 = ks * 4 + (g >> 1), half = (g & 1) * 8;
                s16x4 va0 = *(const s16x4*)(vb2 + row * 128 + ((sl0 ^ (row & 7)) << 4) + half);
                s16x4 va1 = *(const s16x4*)(vb2 + row * 128 + (((sl0 + 2) ^ (row & 7)) << 4) + half);
                s16x8 vf = {va0[0], va0[1], va0[2], va0[3], va1[0], va1[1], va1[2], va1[3]};
                oA[df] = __builtin_amdgcn_mfma_f32_16x16x32_bf16(vf, pbA, oA[df], 0, 0, 0);
                oB[df] = __builtin_amdgcn_mfma_f32_16x16x32_bf16(vf, pbB, oB[df], 0, 0, 0);
            }
        }
    }

    // epilogue: lane owns q = q0+r (A), q0+16+r (B); d = df*16 + g*4 + qi
    float ivA = 1.f / lA, ivB = 1.f / lB;
#pragma unroll
    for (int df = 0; df < 4; ++df) {
        s16x4 oa, ob;
#pragma unroll
        for (int qi = 0; qi < 4; ++qi) {
            oa[qi] = f2b(oA[df][qi] * ivA);
            ob[qi] = f2b(oB[df][qi] * ivB);
        }
        *(s16x4*)&outp[(size_t)(b * 1024 + q0 + r) * 1024 + h * 64 + df * 16 + g * 4] = oa;
        *(s16x4*)&outp[(size_t)(b * 1024 + q0 + 16 + r) * 1024 + h * 64 + df * 16 + g * 4] = ob;
    }
}

// ---------------- launch ----------------
extern "C" void kernel_launch(void* const* d_in, const int* in_sizes, int n_in,
                              void* d_out, int out_size, void* d_ws, size_t ws_size,
                              hipStream_t stream) {
    const float* v  = (const float*)d_in[0];
    const float* k  = (const float*)d_in[1];
    const float* q  = (const float*)d_in[2];
    const float* rr = (const float*)d_in[3];
    const int* mask = (const int*)d_in[4];
    const float* Wv = (const float*)d_in[5];  const float* bv = (const float*)d_in[6];
    const float* Wk = (const float*)d_in[7];  const float* bk = (const float*)d_in[8];
    const float* Wq = (const float*)d_in[9];  const float* bq = (const float*)d_in[10];
    const float* Wr = (const float*)d_in[11]; const float* br = (const float*)d_in[12];
    const float* Wm = (const float*)d_in[13]; const float* bm = (const float*)d_in[14];

    const size_t MB = 1048576u;
    const size_t NEED_FULL = 90u * MB;
    const size_t NEED_B    = 74u * MB;
    char* ws = (char*)d_ws;
    short* Wb = (short*)ws;

    Ptr5 p5;
    p5.p[0] = Wv; p5.p[1] = Wk; p5.p[2] = Wq; p5.p[3] = Wr; p5.p[4] = Wm;
    cvtW<<<dim3(512, 5), 256, 0, stream>>>(p5, Wb);

    const short* Wvb = Wb, *Wkb = Wb + 1048576u, *Wqb = Wb + 2097152u,
               *Wrb = Wb + 3145728u, *Wmb = Wb + 4194304u;
    dim3 gg(512);

    if (ws_size >= NEED_FULL) {
        short* vb  = (short*)(ws + 10u * MB);
        short* kb  = vb + 8388608u;
        short* qb  = kb + 8388608u;
        short* rb  = qb + 8388608u;
        short* vtb = rb + 8388608u;
        short* khb = vb;
        short* qrb = kb;
        short* att = qb;

        Ptr4 p4; p4.p[0] = v; p4.p[1] = k; p4.p[2] = q; p4.p[3] = rr;
        cvtA<<<dim3(4096, 4), 256, 0, stream>>>(p4, vb);

        gemm_nt<0, 2, 0><<<gg, 256, 0, stream>>>(vb, nullptr, Wvb, nullptr, bv, nullptr, vtb);
        gemm_nt<0, 0, 0><<<gg, 256, 0, stream>>>(kb, nullptr, Wkb, nullptr, bk, nullptr, khb);
        gemm_nt<0, 0, 1><<<gg, 256, 0, stream>>>(qb, rb, Wqb, Wrb, bq, br, qrb);
        attn_fwd<<<dim3(128, 8), 256, 0, stream>>>(qrb, khb, vtb, mask, att);
        gemm_nt<0, 1, 0><<<gg, 256, 0, stream>>>(att, nullptr, Wmb, nullptr, bm, nullptr, (float*)d_out);
    } else if (ws_size >= NEED_B) {
        short* kb  = (short*)(ws + 10u * MB);
        short* qb  = kb + 8388608u;
        short* rb  = qb + 8388608u;
        short* qrb = rb + 8388608u;
        short* vtb = qb;
        short* khb = rb;
        short* att = kb;

        Ptr4 p4; p4.p[0] = k; p4.p[1] = q; p4.p[2] = rr; p4.p[3] = k;
        cvtA<<<dim3(4096, 3), 256, 0, stream>>>(p4, kb);

        gemm_nt<0, 0, 1><<<gg, 256, 0, stream>>>(qb, rb, Wqb, Wrb, bq, br, qrb);
        gemm_nt<1, 2, 0><<<gg, 256, 0, stream>>>(v, nullptr, Wvb, nullptr, bv, nullptr, vtb);
        gemm_nt<0, 0, 0><<<gg, 256, 0, stream>>>(kb, nullptr, Wkb, nullptr, bk, nullptr, khb);
        attn_fwd<<<dim3(128, 8), 256, 0, stream>>>(qrb, khb, vtb, mask, att);
        gemm_nt<0, 1, 0><<<gg, 256, 0, stream>>>(att, nullptr, Wmb, nullptr, bm, nullptr, (float*)d_out);
    }
    // else: insufficient ws -> leave poison (visible failure)
}

// Round 6
// 242.571 us; speedup vs baseline: 1.4675x; 1.0444x over previous
//
#include <hip/hip_runtime.h>
#include <hip/hip_bf16.h>
#include <stdint.h>

typedef __attribute__((ext_vector_type(4))) float f32x4;
typedef __attribute__((ext_vector_type(8))) short s16x8;
typedef __attribute__((ext_vector_type(4))) short s16x4;
typedef __attribute__((ext_vector_type(4))) int i32x4;

typedef const __attribute__((address_space(1))) unsigned glb_u32;
typedef __attribute__((address_space(3))) unsigned lds_u32;

#define DEVI __device__ __forceinline__

DEVI short f2b(float f) {
    union { float f; unsigned u; } v; v.f = f;
    unsigned r = v.u + 0x7fffu + ((v.u >> 16) & 1u);
    return (short)(r >> 16);
}

DEVI float vexp2(float x) {           // raw v_exp_f32: 2^x
    float r;
    asm("v_exp_f32 %0, %1" : "=v"(r) : "v"(x));
    return r;
}

DEVI float vmax3(float a, float b, float c) {
    float d;
    asm("v_max3_f32 %0, %1, %2, %3" : "=v"(d) : "v"(a), "v"(b), "v"(c));
    return d;
}

DEVI unsigned cvtpk(float lo, float hi) {   // d.bf16[0]=lo, d.bf16[1]=hi (VOP3 cvt_pk convention)
    unsigned d;
    asm("v_cvt_pk_bf16_f32 %0, %1, %2" : "=v"(d) : "v"(lo), "v"(hi));
    return d;
}

DEVI s16x8 pack8(const f32x4& a, const f32x4& b) {  // v[0..3]=a, v[4..7]=b
    union { unsigned u[4]; s16x8 v; } w;
    w.u[0] = cvtpk(a[0], a[1]);
    w.u[1] = cvtpk(a[2], a[3]);
    w.u[2] = cvtpk(b[0], b[1]);
    w.u[3] = cvtpk(b[2], b[3]);
    return w.v;
}

// exp2-domain constants: score' = score*log2e, so exp(score-m) == exp2(score'-m')
#define QSCL 0.18033688011112042f      /* 0.125 * log2(e) */
#define MASKV -1.4426950408889634e9f   /* -1e9 * log2(e) */

// ---------------- converts: f32 -> bf16 ----------------
struct Ptr5 { const float* p[5]; };
struct Ptr4 { const float* p[4]; };

__global__ __launch_bounds__(256) void cvtW(Ptr5 src, short* __restrict__ dst) {
    const float* s = src.p[blockIdx.y];
    short* d = dst + (size_t)blockIdx.y * (1024u * 1024u);
    int i = (blockIdx.x * 256 + threadIdx.x) * 8;
    f32x4 a = *(const f32x4*)(s + i);
    f32x4 b = *(const f32x4*)(s + i + 4);
    s16x8 o;
#pragma unroll
    for (int j = 0; j < 4; ++j) { o[j] = f2b(a[j]); o[4 + j] = f2b(b[j]); }
    *(s16x8*)(d + i) = o;
}

__global__ __launch_bounds__(256) void cvtA(Ptr4 src, short* __restrict__ dst) {
    const float* s = src.p[blockIdx.y];
    short* d = dst + (size_t)blockIdx.y * (8u * 1024u * 1024u);
    int i = (blockIdx.x * 256 + threadIdx.x) * 8;
    f32x4 a = *(const f32x4*)(s + i);
    f32x4 b = *(const f32x4*)(s + i + 4);
    s16x8 o;
#pragma unroll
    for (int j = 0; j < 4; ++j) { o[j] = f2b(a[j]); o[4 + j] = f2b(b[j]); }
    *(s16x8*)(d + i) = o;
}

// ---------------- NT GEMM: C[M=8192][N=1024] = A[M][K] * W[N][K]^T + bias ----
// AF32: A is f32 (reg-staged with convert); else bf16 via global_load_lds.
// OUTMODE: 0 = bf16 row-major, 1 = f32 row-major, 2 = bf16 per-head-transposed
//          [b][h][d][pos] with pos = pi(tok) permuted within 32-tok blocks:
//          pos[4:3]=tok[3:2], pos[2]=tok[4], pos[1:0]=tok[1:0]  (for attn V,
//          makes each PV A-fragment one contiguous b128 under the XOR swizzle).
// TWO: C = A0*W0^T + A1*W1^T + b0 + b1 (K=2*1024).
template<int AF32, int OUTMODE, int TWO>
__global__ __launch_bounds__(256) void gemm_nt(
    const void* __restrict__ A0_, const void* __restrict__ A1_,
    const short* __restrict__ W0, const short* __restrict__ W1,
    const float* __restrict__ b0, const float* __restrict__ b1,
    void* __restrict__ C_)
{
    constexpr int K = 1024, N = 1024;
    const int tid = threadIdx.x;
    const int lane = tid & 63, wid = tid >> 6;
    const int wm = wid >> 1, wn = wid & 1;
    const int r = lane & 15, g = lane >> 4;

    // XCD-chunked bijective swizzle: 512 blocks, XCD p%8 owns logical [64p%8, ...)
    const int bid = blockIdx.x;
    const int logical = (bid & 7) * 64 + (bid >> 3);
    const int n0 = (logical & 7) * 128, m0 = (logical >> 3) * 128;

    __shared__ alignas(16) short As[2][128 * 32];   // linear [row][32]
    __shared__ alignas(16) short Ws[2][128 * 32];

    auto stage_async = [&](int buf, int kt) {
        int kk = kt * 32;
        const short* Ap = (const short*)A0_; const short* Wp = W0;
        if (TWO && kk >= 1024) { Ap = (const short*)A1_; Wp = W1; kk &= 1023; }
#pragma unroll
        for (int i = 0; i < 2; ++i) {
            int row = wid * 32 + i * 16 + (lane >> 2);
            const short* ga = Ap + (size_t)(m0 + row) * K + kk + (lane & 3) * 8;
            const short* gw = Wp + (size_t)(n0 + row) * K + kk + (lane & 3) * 8;
            __builtin_amdgcn_global_load_lds((glb_u32*)ga,
                (lds_u32*)&As[buf][(wid * 32 + i * 16) * 32], 16, 0, 0);
            __builtin_amdgcn_global_load_lds((glb_u32*)gw,
                (lds_u32*)&Ws[buf][(wid * 32 + i * 16) * 32], 16, 0, 0);
        }
    };

    const int srow = tid >> 1, shalf = tid & 1;
    f32x4 a0g, a1g, a2g, a3g;
    s16x8 wg0, wg1;
    auto load_regs = [&](int kt) {
        int kk = kt * 32;
        const short* wp = W0 + (size_t)(n0 + srow) * K + kk + shalf * 16;
        wg0 = *(const s16x8*)wp;
        wg1 = *(const s16x8*)(wp + 8);
        const float* ap = (const float*)A0_ + (size_t)(m0 + srow) * K + kk + shalf * 16;
        a0g = *(const f32x4*)ap;       a1g = *(const f32x4*)(ap + 4);
        a2g = *(const f32x4*)(ap + 8); a3g = *(const f32x4*)(ap + 12);
    };
    auto store_lds = [&](int buf) {
        s16x8 s0, s1;
#pragma unroll
        for (int j = 0; j < 4; ++j) {
            s0[j] = f2b(a0g[j]); s0[4 + j] = f2b(a1g[j]);
            s1[j] = f2b(a2g[j]); s1[4 + j] = f2b(a3g[j]);
        }
        char* ab = (char*)As[buf];
        *(s16x8*)(ab + srow * 64 + shalf * 32) = s0;
        *(s16x8*)(ab + srow * 64 + shalf * 32 + 16) = s1;
        char* wb = (char*)Ws[buf];
        *(s16x8*)(wb + srow * 64 + shalf * 32) = wg0;
        *(s16x8*)(wb + srow * 64 + shalf * 32 + 16) = wg1;
    };

    f32x4 z = {0.f, 0.f, 0.f, 0.f};
    f32x4 acc[4][4];
#pragma unroll
    for (int i = 0; i < 4; ++i)
#pragma unroll
        for (int j = 0; j < 4; ++j) acc[i][j] = z;

    auto compute = [&](int buf) {
        s16x8 af[4], bfr[4];
#pragma unroll
        for (int f = 0; f < 4; ++f) {
            af[f]  = *(const s16x8*)&As[buf][(wm * 64 + f * 16 + r) * 32 + g * 8];
            bfr[f] = *(const s16x8*)&Ws[buf][(wn * 64 + f * 16 + r) * 32 + g * 8];
        }
#pragma unroll
        for (int i = 0; i < 4; ++i)
#pragma unroll
            for (int j = 0; j < 4; ++j)
                acc[i][j] = __builtin_amdgcn_mfma_f32_16x16x32_bf16(af[i], bfr[j], acc[i][j], 0, 0, 0);
    };

    constexpr int NK = TWO ? 64 : 32;
    if constexpr (AF32) { load_regs(0); store_lds(0); }
    else stage_async(0, 0);
    __syncthreads();
    int buf = 0;
    for (int kt = 0; kt < NK; ++kt) {
        if (kt + 1 < NK) {
            if constexpr (AF32) load_regs(kt + 1);
            else stage_async(buf ^ 1, kt + 1);
        }
        compute(buf);
        if (AF32 && kt + 1 < NK) store_lds(buf ^ 1);
        __syncthreads();
        buf ^= 1;
    }

    // epilogue: C layout col=lane&15, row=(lane>>4)*4+reg
#pragma unroll
    for (int j = 0; j < 4; ++j) {
        int col = n0 + wn * 64 + j * 16 + r;
        float bb = b0[col];
        if (TWO) bb += b1[col];
#pragma unroll
        for (int i = 0; i < 4; ++i) {
            int rowb = m0 + wm * 64 + i * 16 + g * 4;
            if constexpr (OUTMODE == 2) {
                // V^T per head, pi-permuted pos (rowb%4==0 so tok[1:0]=0)
                int bb_ = rowb >> 10, tok = rowb & 1023;
                int tokp = (tok & ~31) | (((tok >> 2) & 3) << 3) | (((tok >> 4) & 1) << 2);
                short* dst = (short*)C_ + ((size_t)(bb_ * 16 + (col >> 6))) * 65536
                           + (size_t)(col & 63) * 1024 + tokp;
                s16x4 o;
#pragma unroll
                for (int q = 0; q < 4; ++q) o[q] = f2b(acc[i][j][q] + bb);
                *(s16x4*)dst = o;
            } else {
#pragma unroll
                for (int q = 0; q < 4; ++q) {
                    float val = acc[i][j][q] + bb;
                    if constexpr (OUTMODE == 1)
                        ((float*)C_)[(size_t)(rowb + q) * N + col] = val;
                    else
                        ((short*)C_)[(size_t)(rowb + q) * N + col] = f2b(val);
                }
            }
        }
    }
}

// ---------------- flash attention v4 ----------------------------------------
// Round-5 verified structure + {pi+b128 PV, cvtpk pack, exp2-domain, max3}.
// grid (128 bh, 8 qt); block 256 = 4 waves; wave handles 32 q-rows (2 groups).
__global__ __launch_bounds__(256) void attn_fwd(
    const short* __restrict__ qrh, const short* __restrict__ kh,
    const short* __restrict__ vT, const int* __restrict__ mask,
    short* __restrict__ outp)
{
    const int bh = blockIdx.x;
    const int b = bh >> 4, h = bh & 15;
    const int qt = blockIdx.y;
    const int tid = threadIdx.x, lane = tid & 63, wid = tid >> 6;
    const int r = lane & 15, g = lane >> 4;

    __shared__ alignas(16) short Ks[64 * 64];   // [tok][d], 16B slot ^= row&7
    __shared__ alignas(16) short Vs[64 * 64];   // [d][pos], same swizzle
    __shared__ alignas(16) float mb[1024];      // premask (exp2 domain), whole row

    {   // premask: mask[b][tok] ? MASKV : 0
        i32x4 mi = *(const i32x4*)(mask + b * 1024 + tid * 4);
        f32x4 mv;
#pragma unroll
        for (int j = 0; j < 4; ++j) mv[j] = mi[j] ? MASKV : 0.f;
        *(f32x4*)&mb[tid * 4] = mv;
    }

    const int q0 = qt * 128 + wid * 32;
    const short* qbA = qrh + (size_t)(b * 1024 + q0 + r) * 1024 + h * 64;
    const short* qbB = qbA + 16 * 1024;
    s16x8 qA0 = *(const s16x8*)(qbA + g * 8);
    s16x8 qA1 = *(const s16x8*)(qbA + 32 + g * 8);
    s16x8 qB0 = *(const s16x8*)(qbB + g * 8);
    s16x8 qB1 = *(const s16x8*)(qbB + 32 + g * 8);

    f32x4 z = {0.f, 0.f, 0.f, 0.f};
    f32x4 oA[4], oB[4];
#pragma unroll
    for (int i = 0; i < 4; ++i) { oA[i] = z; oB[i] = z; }
    float mA = -1e30f, mB = -1e30f, lA = 0.f, lB = 0.f;

    // staging: thread (srow, sq) covers row srow, 16 elems at sq*16
    const int srow = tid >> 2, sq = tid & 3;
    const short* kg = kh + (size_t)(b * 1024 + srow) * 1024 + h * 64 + sq * 16;
    const short* vg = vT + ((size_t)(b * 16 + h)) * 65536 + (size_t)srow * 1024 + sq * 16;
    const int p0s = (sq * 2) ^ (srow & 7), p1s = (sq * 2 + 1) ^ (srow & 7);

    s16x8 kr0, kr1, vr0, vr1;
    auto stage_load = [&](int t) {
        const short* kp = kg + (size_t)(t * 64) * 1024;
        kr0 = *(const s16x8*)kp; kr1 = *(const s16x8*)(kp + 8);
        const short* vp = vg + t * 64;
        vr0 = *(const s16x8*)vp; vr1 = *(const s16x8*)(vp + 8);
    };
    auto stage_write = [&]() {
        char* kb2 = (char*)Ks;
        *(s16x8*)(kb2 + srow * 128 + p0s * 16) = kr0;
        *(s16x8*)(kb2 + srow * 128 + p1s * 16) = kr1;
        char* vb2 = (char*)Vs;
        *(s16x8*)(vb2 + srow * 128 + p0s * 16) = vr0;
        *(s16x8*)(vb2 + srow * 128 + p1s * 16) = vr1;
    };

    stage_load(0);
    for (int t = 0; t < 16; ++t) {
        if (t) __syncthreads();
        stage_write();
        __syncthreads();
        if (t < 15) stage_load(t + 1);   // T14: issue next tile loads early

        // QK^T swapped: lane holds q=r (grpA) / q=16+r (grpB), toks fn*16+g*4+qi
        f32x4 pA[4], pB[4];
        float tmA = -3e38f, tmB = -3e38f;
        char* kb2 = (char*)Ks;
#pragma unroll
        for (int fn = 0; fn < 4; ++fn) {
            int row = fn * 16 + r;
            s16x8 kfa = *(const s16x8*)(kb2 + row * 128 + ((g ^ (row & 7)) << 4));
            s16x8 kfb = *(const s16x8*)(kb2 + row * 128 + (((4 + g) ^ (row & 7)) << 4));
            f32x4 cA = __builtin_amdgcn_mfma_f32_16x16x32_bf16(kfa, qA0, z, 0, 0, 0);
            cA = __builtin_amdgcn_mfma_f32_16x16x32_bf16(kfb, qA1, cA, 0, 0, 0);
            f32x4 cB = __builtin_amdgcn_mfma_f32_16x16x32_bf16(kfa, qB0, z, 0, 0, 0);
            cB = __builtin_amdgcn_mfma_f32_16x16x32_bf16(kfb, qB1, cB, 0, 0, 0);
            f32x4 mv = *(const f32x4*)&mb[t * 64 + fn * 16 + g * 4];
#pragma unroll
            for (int qi = 0; qi < 4; ++qi) {
                pA[fn][qi] = cA[qi] * QSCL + mv[qi];
                pB[fn][qi] = cB[qi] * QSCL + mv[qi];
            }
            tmA = vmax3(tmA, pA[fn][0], pA[fn][1]);
            tmA = vmax3(tmA, pA[fn][2], pA[fn][3]);
            tmB = vmax3(tmB, pB[fn][0], pB[fn][1]);
            tmB = vmax3(tmB, pB[fn][2], pB[fn][3]);
        }
        tmA = fmaxf(tmA, __shfl_xor(tmA, 16)); tmA = fmaxf(tmA, __shfl_xor(tmA, 32));
        tmB = fmaxf(tmB, __shfl_xor(tmB, 16)); tmB = fmaxf(tmB, __shfl_xor(tmB, 32));

        // online softmax (exp2 domain), unconditional rescale
        float mnA = fmaxf(mA, tmA), mnB = fmaxf(mB, tmB);
        float cA_ = vexp2(mA - mnA), cB_ = vexp2(mB - mnB);
        mA = mnA; mB = mnB;
        float tsA = 0.f, tsB = 0.f;
#pragma unroll
        for (int fn = 0; fn < 4; ++fn)
#pragma unroll
            for (int qi = 0; qi < 4; ++qi) {
                float eA = vexp2(pA[fn][qi] - mA); pA[fn][qi] = eA; tsA += eA;
                float eB = vexp2(pB[fn][qi] - mB); pB[fn][qi] = eB; tsB += eB;
            }
        tsA += __shfl_xor(tsA, 16); tsA += __shfl_xor(tsA, 32);
        tsB += __shfl_xor(tsB, 16); tsB += __shfl_xor(tsB, 32);
        lA = lA * cA_ + tsA; lB = lB * cB_ + tsB;
#pragma unroll
        for (int df = 0; df < 4; ++df)
#pragma unroll
            for (int qi = 0; qi < 4; ++qi) { oA[df][qi] *= cA_; oB[df][qi] *= cB_; }

        // PV: pi-permuted V -> one b128 A-frag per (ks,df); shared k-mapping:
        //   (g,j) -> tok = ks*32 + (j>=4)*16 + 4g + (j&3); pos = ks*32 + g*8 + j
        char* vb2 = (char*)Vs;
#pragma unroll
        for (int ks = 0; ks < 2; ++ks) {
            s16x8 pbA = pack8(pA[2 * ks], pA[2 * ks + 1]);
            s16x8 pbB = pack8(pB[2 * ks], pB[2 * ks + 1]);
#pragma unroll
            for (int df = 0; df < 4; ++df) {
                int row = df * 16 + r;
                int slot = (ks * 4 + g) ^ (row & 7);
                s16x8 vf = *(const s16x8*)(vb2 + row * 128 + (slot << 4));
                oA[df] = __builtin_amdgcn_mfma_f32_16x16x32_bf16(vf, pbA, oA[df], 0, 0, 0);
                oB[df] = __builtin_amdgcn_mfma_f32_16x16x32_bf16(vf, pbB, oB[df], 0, 0, 0);
            }
        }
    }

    // epilogue: lane owns q = q0+r (A), q0+16+r (B); d = df*16 + g*4 + qi
    float ivA = 1.f / lA, ivB = 1.f / lB;
#pragma unroll
    for (int df = 0; df < 4; ++df) {
        s16x4 oa, ob;
#pragma unroll
        for (int qi = 0; qi < 4; ++qi) {
            oa[qi] = f2b(oA[df][qi] * ivA);
            ob[qi] = f2b(oB[df][qi] * ivB);
        }
        *(s16x4*)&outp[(size_t)(b * 1024 + q0 + r) * 1024 + h * 64 + df * 16 + g * 4] = oa;
        *(s16x4*)&outp[(size_t)(b * 1024 + q0 + 16 + r) * 1024 + h * 64 + df * 16 + g * 4] = ob;
    }
}

// ---------------- launch ----------------
extern "C" void kernel_launch(void* const* d_in, const int* in_sizes, int n_in,
                              void* d_out, int out_size, void* d_ws, size_t ws_size,
                              hipStream_t stream) {
    const float* v  = (const float*)d_in[0];
    const float* k  = (const float*)d_in[1];
    const float* q  = (const float*)d_in[2];
    const float* rr = (const float*)d_in[3];
    const int* mask = (const int*)d_in[4];
    const float* Wv = (const float*)d_in[5];  const float* bv = (const float*)d_in[6];
    const float* Wk = (const float*)d_in[7];  const float* bk = (const float*)d_in[8];
    const float* Wq = (const float*)d_in[9];  const float* bq = (const float*)d_in[10];
    const float* Wr = (const float*)d_in[11]; const float* br = (const float*)d_in[12];
    const float* Wm = (const float*)d_in[13]; const float* bm = (const float*)d_in[14];

    const size_t MB = 1048576u;
    const size_t NEED_FULL = 90u * MB;
    const size_t NEED_B    = 74u * MB;
    char* ws = (char*)d_ws;
    short* Wb = (short*)ws;

    Ptr5 p5;
    p5.p[0] = Wv; p5.p[1] = Wk; p5.p[2] = Wq; p5.p[3] = Wr; p5.p[4] = Wm;
    cvtW<<<dim3(512, 5), 256, 0, stream>>>(p5, Wb);

    const short* Wvb = Wb, *Wkb = Wb + 1048576u, *Wqb = Wb + 2097152u,
               *Wrb = Wb + 3145728u, *Wmb = Wb + 4194304u;
    dim3 gg(512);

    if (ws_size >= NEED_FULL) {
        short* vb  = (short*)(ws + 10u * MB);
        short* kb  = vb + 8388608u;
        short* qb  = kb + 8388608u;
        short* rb  = qb + 8388608u;
        short* vtb = rb + 8388608u;
        short* khb = vb;
        short* qrb = kb;
        short* att = qb;

        Ptr4 p4; p4.p[0] = v; p4.p[1] = k; p4.p[2] = q; p4.p[3] = rr;
        cvtA<<<dim3(4096, 4), 256, 0, stream>>>(p4, vb);

        gemm_nt<0, 2, 0><<<gg, 256, 0, stream>>>(vb, nullptr, Wvb, nullptr, bv, nullptr, vtb);
        gemm_nt<0, 0, 0><<<gg, 256, 0, stream>>>(kb, nullptr, Wkb, nullptr, bk, nullptr, khb);
        gemm_nt<0, 0, 1><<<gg, 256, 0, stream>>>(qb, rb, Wqb, Wrb, bq, br, qrb);
        attn_fwd<<<dim3(128, 8), 256, 0, stream>>>(qrb, khb, vtb, mask, att);
        gemm_nt<0, 1, 0><<<gg, 256, 0, stream>>>(att, nullptr, Wmb, nullptr, bm, nullptr, (float*)d_out);
    } else if (ws_size >= NEED_B) {
        short* kb  = (short*)(ws + 10u * MB);
        short* qb  = kb + 8388608u;
        short* rb  = qb + 8388608u;
        short* qrb = rb + 8388608u;
        short* vtb = qb;
        short* khb = rb;
        short* att = kb;

        Ptr4 p4; p4.p[0] = k; p4.p[1] = q; p4.p[2] = rr; p4.p[3] = k;
        cvtA<<<dim3(4096, 3), 256, 0, stream>>>(p4, kb);

        gemm_nt<0, 0, 1><<<gg, 256, 0, stream>>>(qb, rb, Wqb, Wrb, bq, br, qrb);
        gemm_nt<1, 2, 0><<<gg, 256, 0, stream>>>(v, nullptr, Wvb, nullptr, bv, nullptr, vtb);
        gemm_nt<0, 0, 0><<<gg, 256, 0, stream>>>(kb, nullptr, Wkb, nullptr, bk, nullptr, khb);
        attn_fwd<<<dim3(128, 8), 256, 0, stream>>>(qrb, khb, vtb, mask, att);
        gemm_nt<0, 1, 0><<<gg, 256, 0, stream>>>(att, nullptr, Wmb, nullptr, bm, nullptr, (float*)d_out);
    }
    // else: insufficient ws -> leave poison (visible failure)
}